// Round 12
// baseline (258.705 us; speedup 1.0000x reference)
//
#include <hip/hip_runtime.h>

// B=32, N=512, D=256, M=64, HID=256, H2=128, T=16384, rows R=B*T=524288
typedef _Float16 f16;
typedef f16  f16x2 __attribute__((ext_vector_type(2)));
typedef f16  f16x8 __attribute__((ext_vector_type(8)));
typedef float f32x16 __attribute__((ext_vector_type(16)));
typedef unsigned int u32;

#define MFMA32 __builtin_amdgcn_mfma_f32_32x32x16_f16

static __device__ __forceinline__ f16x8 cvt8(float4 a, float4 b) {
    f16x8 v;
    v[0]=(f16)a.x; v[1]=(f16)a.y; v[2]=(f16)a.z; v[3]=(f16)a.w;
    v[4]=(f16)b.x; v[5]=(f16)b.y; v[6]=(f16)b.z; v[7]=(f16)b.w;
    return v;
}
static __device__ __forceinline__ u32 pack2(float a, float b) {
    f16x2 p; p[0]=(f16)a; p[1]=(f16)b;
    return __builtin_bit_cast(u32, p);
}
static __device__ __forceinline__ u32 pk_add(u32 a, u32 b) {
    u32 d; asm("v_pk_add_f16 %0, %1, %2" : "=v"(d) : "v"(a), "v"(b)); return d;
}
static __device__ __forceinline__ u32 pk_relu(u32 a) {
    u32 d; asm("v_pk_max_f16 %0, %1, 0" : "=v"(d) : "v"(a)); return d;
}

// ---------------------------------------------------------------------------
// Prepack: W1a (256x256), W1b (64x256), W2 (256x128) -> f16 MFMA A-operand
// fragment layout for 32x32x16: frag[mt][ks][lane][j] = W[k][col],
// k = 16*ks + 8*(lane>>5) + j, col = 32*mt + (lane&31).
// Also zeroes the fused kernel's work-stealing counter (runs first in stream).
// ---------------------------------------------------------------------------
__global__ __launch_bounds__(256) void prepack(
    const float* __restrict__ W1, const float* __restrict__ W2,
    f16* __restrict__ pa, f16* __restrict__ pb, f16* __restrict__ pc,
    int* __restrict__ ctr)
{
    if (blockIdx.x == 0 && threadIdx.x == 0) *ctr = 0;
    const int idx = blockIdx.x * 256 + threadIdx.x;   // grid covers 114688
    int rel, fid, mt, ks;
    const int lane = (idx >> 3) & 63;
    const int j    = idx & 7;
    const int g8   = ((lane >> 5) << 3) + j;
    const int ln   = lane & 31;
    if (idx < 65536) {                 // W1a: [8 mt][16 ks]
        rel = idx; fid = rel >> 9; mt = fid >> 4; ks = fid & 15;
        int k = 16 * ks + g8, col = 32 * mt + ln;
        pa[rel] = (f16)W1[k * 256 + col];
    } else if (idx < 81920) {          // W1b: [8 mt][4 ks]
        rel = idx - 65536; fid = rel >> 9; mt = fid >> 2; ks = fid & 3;
        int k = 16 * ks + g8, col = 32 * mt + ln;
        pb[rel] = (f16)W1[(256 + k) * 256 + col];
    } else {                           // W2: [4 mt][16 ks]
        rel = idx - 81920; fid = rel >> 9; mt = fid >> 4; ks = fid & 15;
        int k = 16 * ks + g8, col = 32 * mt + ln;
        pc[rel] = (f16)W2[k * 128 + col];
    }
}

// ---------------------------------------------------------------------------
// Kernel 1: A[ir][c] = sum_k h[ir][k] * W1a[k][c] + b1[c], stored f16 in a
// gather-friendly permuted layout: uint2 index = ir*64 + g*32 + mt*4 + q.
// ---------------------------------------------------------------------------
__global__ __launch_bounds__(256) void ainit(
    const float* __restrict__ H,       // [16384, 256]
    const f16x8* __restrict__ pW1a,    // [8][16][64] frags
    const float* __restrict__ B1,      // [256]
    f16* __restrict__ Af)              // [16384, 256] permuted
{
    const int tid = threadIdx.x, wid = tid >> 6, lane = tid & 63;
    const int g = lane >> 5, ln = lane & 31;
    const long ir = (long)blockIdx.x * 32 + ln;

    const float4* h4 = (const float4*)(H + ir * 256);
    f16x8 hf[16];
    #pragma unroll
    for (int ks = 0; ks < 16; ++ks)
        hf[ks] = cvt8(h4[4 * ks + 2 * g], h4[4 * ks + 2 * g + 1]);

    const float4* b14 = (const float4*)B1;
    #pragma unroll
    for (int mi = 0; mi < 2; ++mi) {
        const int mt = wid * 2 + mi;
        f32x16 acc;
        #pragma unroll
        for (int q = 0; q < 4; ++q) {
            float4 bv = b14[8 * mt + 2 * q + g];
            acc[4*q+0] = bv.x; acc[4*q+1] = bv.y; acc[4*q+2] = bv.z; acc[4*q+3] = bv.w;
        }
        #pragma unroll
        for (int ks = 0; ks < 16; ++ks)
            acc = MFMA32(pW1a[(mt * 16 + ks) * 64 + lane], hf[ks], acc, 0, 0, 0);
        #pragma unroll
        for (int q = 0; q < 4; ++q) {
            uint2 w;
            w.x = pack2(acc[4*q+0], acc[4*q+1]);
            w.y = pack2(acc[4*q+2], acc[4*q+3]);
            ((uint2*)Af)[ir * 64 + g * 32 + mt * 4 + q] = w;
        }
    }
}

// ---------------------------------------------------------------------------
// Fused: h1 = relu(me@W1b + A[seg]); h2 = relu(h1@W2 + b2); out = h2@W3 + b3
// 256 blocks x 768 threads (12 waves = 3/SIMD, 1 block/CU, 96 KB LDS).
// ATOMIC WORK-STEALING: each wave grabs one 32-row tile at a time; the next
// grab + its SEG read are issued a full tile ahead (latency hidden).
// Per tile: rolling depth-2-mt Af prefetch, JIT ME, no barriers.
// ---------------------------------------------------------------------------
__global__ __launch_bounds__(768, 3) void fused_mlp(
    const float* __restrict__ ME,      // [524288, 64]
    const int*   __restrict__ SEG,     // [16384]
    const f16*   __restrict__ Af,      // [16384, 256] permuted
    const f16x8* __restrict__ pW1b,    // [8][4][64] frags
    const f16x8* __restrict__ pW2,     // [4][16][64] frags
    const float* __restrict__ B2,      // [128]
    const float* __restrict__ W3,      // [128]
    const float* __restrict__ B3,      // [1]
    int* __restrict__ ctr,             // work-stealing counter (zeroed by prepack)
    float* __restrict__ OUT)           // [524288]
{
    __shared__ f16x8 sW1b[2048];       // 32 KB
    __shared__ f16x8 sW2[4096];        // 64 KB
    const int tid = threadIdx.x, lane = tid & 63;
    const int g = lane >> 5, ln = lane & 31;

    for (int i = tid; i < 2048; i += 768) sW1b[i] = pW1b[i];
    for (int i = tid; i < 4096; i += 768) sW2[i]  = pW2[i];
    __syncthreads();

    const uint4* AB = (const uint4*)Af;   // 16B units: row*32 + g*16 + u
    const float4* b24 = (const float4*)B2;
    const float4* w34 = (const float4*)W3;
    const float  b3v  = B3[0];

    // initial grab + SEG for it (one exposed hop at kernel start only)
    int cur;
    if (lane == 0) cur = atomicAdd(ctr, 1);
    cur = __builtin_amdgcn_readfirstlane(cur);
    if (cur >= 16384) return;
    int sv_cur = SEG[((cur & 511) << 5) + ln];

    while (true) {
        // grab next tile + issue its SEG read (a full tile of cover)
        int nxt;
        if (lane == 0) nxt = atomicAdd(ctr, 1);
        nxt = __builtin_amdgcn_readfirstlane(nxt);
        int sv_nxt = 0;
        if (nxt < 16384) sv_nxt = SEG[((nxt & 511) << 5) + ln];

        const long row_base = (long)cur << 5;
        const int  ar = ((cur >> 9) << 9) + sv_cur;   // per-lane gather row

        // Av prologue: slots for mt 0,1
        uint4 Av[4];
        #pragma unroll
        for (int u = 0; u < 4; ++u) Av[u] = AB[(long)ar * 32 + g * 16 + u];

        // ME fragments (JIT; loads first, cvt after)
        const float4* mb = (const float4*)(ME + (row_base + ln) * 64);
        float4 m0 = mb[2*g],      m1 = mb[2*g + 1];
        float4 m2_ = mb[4 + 2*g], m3 = mb[4 + 2*g + 1];
        float4 m4 = mb[8 + 2*g],  m5 = mb[8 + 2*g + 1];
        float4 m6 = mb[12 + 2*g], m7 = mb[12 + 2*g + 1];
        f16x8 mef[4];
        mef[0] = cvt8(m0, m1);  mef[1] = cvt8(m2_, m3);
        mef[2] = cvt8(m4, m5);  mef[3] = cvt8(m6, m7);

        f32x16 acc2[4];
        #pragma unroll
        for (int m2 = 0; m2 < 4; ++m2)
            #pragma unroll
            for (int i = 0; i < 16; ++i) acc2[m2][i] = 0.f;

        #pragma unroll
        for (int mt = 0; mt < 8; ++mt) {
            const int sl = (mt & 1) * 2;
            const uint4 a0 = Av[sl], a1 = Av[sl + 1];
            // refill this rolling slot for position mt+2 (within tile)
            {
                const int pos = mt + 2;
                if (pos < 8) {
                    Av[sl]     = AB[(long)ar * 32 + g * 16 + 2*pos];
                    Av[sl + 1] = AB[(long)ar * 32 + g * 16 + 2*pos + 1];
                }
            }

            // layer-1 partial: me @ W1b (this mt's 32 cols), W1b from LDS
            f32x16 acc;
            #pragma unroll
            for (int i = 0; i < 16; ++i) acc[i] = 0.f;
            #pragma unroll
            for (int s = 0; s < 4; ++s)
                acc = MFMA32(sW1b[(mt * 4 + s) * 64 + lane], mef[s], acc, 0, 0, 0);

            // h1 = relu(A + mw) in packed f16
            u32 hpt[8];
            hpt[0] = pk_relu(pk_add(pack2(acc[0],  acc[1]),  a0.x));
            hpt[1] = pk_relu(pk_add(pack2(acc[2],  acc[3]),  a0.y));
            hpt[2] = pk_relu(pk_add(pack2(acc[4],  acc[5]),  a0.z));
            hpt[3] = pk_relu(pk_add(pack2(acc[6],  acc[7]),  a0.w));
            hpt[4] = pk_relu(pk_add(pack2(acc[8],  acc[9]),  a1.x));
            hpt[5] = pk_relu(pk_add(pack2(acc[10], acc[11]), a1.y));
            hpt[6] = pk_relu(pk_add(pack2(acc[12], acc[13]), a1.z));
            hpt[7] = pk_relu(pk_add(pack2(acc[14], acc[15]), a1.w));

            // layer-2 feed: ks2 = 2*mt + tt, W2 from LDS
            #pragma unroll
            for (int tt = 0; tt < 2; ++tt) {
                u32 w0 = hpt[4*tt+0], w1 = hpt[4*tt+1];
                u32 w2 = hpt[4*tt+2], w3 = hpt[4*tt+3];
                asm("v_permlane32_swap_b32 %0, %1" : "+v"(w0), "+v"(w2));
                asm("v_permlane32_swap_b32 %0, %1" : "+v"(w1), "+v"(w3));
                int wv[4] = {(int)w0, (int)w1, (int)w2, (int)w3};
                f16x8 bf;
                __builtin_memcpy(&bf, wv, 16);
                const int ks2 = 2 * mt + tt;
                __builtin_amdgcn_s_setprio(1);
                #pragma unroll
                for (int m2 = 0; m2 < 4; ++m2)
                    acc2[m2] = MFMA32(sW2[(m2 * 16 + ks2) * 64 + lane], bf, acc2[m2], 0, 0, 0);
                __builtin_amdgcn_s_setprio(0);
            }
        }

        // phase 3: out = relu(h2 + b2) . W3 + b3
        float sum = 0.f;
        #pragma unroll
        for (int m2 = 0; m2 < 4; ++m2)
            #pragma unroll
            for (int q = 0; q < 4; ++q) {
                float4 bb = b24[8*m2 + 2*q + g];
                float4 ww = w34[8*m2 + 2*q + g];
                sum += fmaxf(acc2[m2][4*q+0] + bb.x, 0.f) * ww.x
                     + fmaxf(acc2[m2][4*q+1] + bb.y, 0.f) * ww.y
                     + fmaxf(acc2[m2][4*q+2] + bb.z, 0.f) * ww.z
                     + fmaxf(acc2[m2][4*q+3] + bb.w, 0.f) * ww.w;
            }
        sum += __shfl_xor(sum, 32, 64);     // combine the two g column-halves
        if (lane < 32) OUT[row_base + ln] = sum + b3v;

        if (nxt >= 16384) break;
        cur = nxt;
        sv_cur = sv_nxt;
    }
}

// ---------------------------------------------------------------------------
extern "C" void kernel_launch(void* const* d_in, const int* in_sizes, int n_in,
                              void* d_out, int out_size, void* d_ws, size_t ws_size,
                              hipStream_t stream) {
    const float* h_inst = (const float*)d_in[0];
    const float* me     = (const float*)d_in[1];
    const int*   seg    = (const int*)d_in[2];
    const float* W1     = (const float*)d_in[3];
    const float* b1     = (const float*)d_in[4];
    const float* W2     = (const float*)d_in[5];
    const float* b2     = (const float*)d_in[6];
    const float* W3     = (const float*)d_in[7];
    const float* b3     = (const float*)d_in[8];
    float* out = (float*)d_out;

    char* ws = (char*)d_ws;
    f16* Af   = (f16*)ws;                                   // 8,388,608 B
    f16* pW1a = (f16*)(ws + 8388608);                       //   131,072 B
    f16* pW1b = (f16*)(ws + 8388608 + 131072);              //    32,768 B
    f16* pW2  = (f16*)(ws + 8388608 + 131072 + 32768);      //    65,536 B
    int* ctr  = (int*)(ws + 9437184);                       // stealing counter

    prepack<<<448, 256, 0, stream>>>(W1, W2, pW1a, pW1b, pW2, ctr);
    ainit<<<512, 256, 0, stream>>>(h_inst, (const f16x8*)pW1a, b1, Af);
    fused_mlp<<<256, 768, 0, stream>>>(me, seg, Af, (const f16x8*)pW1b,
                                       (const f16x8*)pW2, b2, W3, b3, ctr, out);
}

// Round 13
// 84.538 us; speedup vs baseline: 3.0602x; 3.0602x over previous
//
#include <hip/hip_runtime.h>

// B=32, N=512, D=256, M=64, HID=256, H2=128, T=16384, rows R=B*T=524288
typedef _Float16 f16;
typedef f16  f16x2 __attribute__((ext_vector_type(2)));
typedef f16  f16x8 __attribute__((ext_vector_type(8)));
typedef float f32x16 __attribute__((ext_vector_type(16)));
typedef unsigned int u32;
typedef unsigned long long u64;

#define MFMA32 __builtin_amdgcn_mfma_f32_32x32x16_f16

static __device__ __forceinline__ f16x8 cvt8(float4 a, float4 b) {
    f16x8 v;
    v[0]=(f16)a.x; v[1]=(f16)a.y; v[2]=(f16)a.z; v[3]=(f16)a.w;
    v[4]=(f16)b.x; v[5]=(f16)b.y; v[6]=(f16)b.z; v[7]=(f16)b.w;
    return v;
}
static __device__ __forceinline__ u32 pack2(float a, float b) {
    f16x2 p; p[0]=(f16)a; p[1]=(f16)b;
    return __builtin_bit_cast(u32, p);
}
static __device__ __forceinline__ u32 pk_add(u32 a, u32 b) {
    u32 d; asm("v_pk_add_f16 %0, %1, %2" : "=v"(d) : "v"(a), "v"(b)); return d;
}
static __device__ __forceinline__ u32 pk_relu(u32 a) {
    u32 d; asm("v_pk_max_f16 %0, %1, 0" : "=v"(d) : "v"(a)); return d;
}

// ---------------------------------------------------------------------------
// Prepack: W1a (256x256), W1b (64x256), W2 (256x128) -> f16 MFMA A-operand
// fragment layout for 32x32x16: frag[mt][ks][lane][j] = W[k][col],
// k = 16*ks + 8*(lane>>5) + j, col = 32*mt + (lane&31).
// ---------------------------------------------------------------------------
__global__ __launch_bounds__(256) void prepack(
    const float* __restrict__ W1, const float* __restrict__ W2,
    f16* __restrict__ pa, f16* __restrict__ pb, f16* __restrict__ pc)
{
    const int idx = blockIdx.x * 256 + threadIdx.x;   // grid covers 114688
    int rel, fid, mt, ks;
    const int lane = (idx >> 3) & 63;
    const int j    = idx & 7;
    const int g8   = ((lane >> 5) << 3) + j;
    const int ln   = lane & 31;
    if (idx < 65536) {                 // W1a: [8 mt][16 ks]
        rel = idx; fid = rel >> 9; mt = fid >> 4; ks = fid & 15;
        int k = 16 * ks + g8, col = 32 * mt + ln;
        pa[rel] = (f16)W1[k * 256 + col];
    } else if (idx < 81920) {          // W1b: [8 mt][4 ks]
        rel = idx - 65536; fid = rel >> 9; mt = fid >> 2; ks = fid & 3;
        int k = 16 * ks + g8, col = 32 * mt + ln;
        pb[rel] = (f16)W1[(256 + k) * 256 + col];
    } else {                           // W2: [4 mt][16 ks]
        rel = idx - 81920; fid = rel >> 9; mt = fid >> 4; ks = fid & 15;
        int k = 16 * ks + g8, col = 32 * mt + ln;
        pc[rel] = (f16)W2[k * 128 + col];
    }
}

// ---------------------------------------------------------------------------
// Kernel 1: A[ir][c] = sum_k h[ir][k] * W1a[k][c] + b1[c], stored f16 in a
// gather-friendly permuted layout: uint2 index = ir*64 + g*32 + mt*4 + q.
// ---------------------------------------------------------------------------
__global__ __launch_bounds__(256) void ainit(
    const float* __restrict__ H,       // [16384, 256]
    const f16x8* __restrict__ pW1a,    // [8][16][64] frags
    const float* __restrict__ B1,      // [256]
    f16* __restrict__ Af)              // [16384, 256] permuted
{
    const int tid = threadIdx.x, wid = tid >> 6, lane = tid & 63;
    const int g = lane >> 5, ln = lane & 31;
    const long ir = (long)blockIdx.x * 32 + ln;

    const float4* h4 = (const float4*)(H + ir * 256);
    f16x8 hf[16];
    #pragma unroll
    for (int ks = 0; ks < 16; ++ks)
        hf[ks] = cvt8(h4[4 * ks + 2 * g], h4[4 * ks + 2 * g + 1]);

    const float4* b14 = (const float4*)B1;
    #pragma unroll
    for (int mi = 0; mi < 2; ++mi) {
        const int mt = wid * 2 + mi;
        f32x16 acc;
        #pragma unroll
        for (int q = 0; q < 4; ++q) {
            float4 bv = b14[8 * mt + 2 * q + g];
            acc[4*q+0] = bv.x; acc[4*q+1] = bv.y; acc[4*q+2] = bv.z; acc[4*q+3] = bv.w;
        }
        #pragma unroll
        for (int ks = 0; ks < 16; ++ks)
            acc = MFMA32(pW1a[(mt * 16 + ks) * 64 + lane], hf[ks], acc, 0, 0, 0);
        #pragma unroll
        for (int q = 0; q < 4; ++q) {
            uint2 w;
            w.x = pack2(acc[4*q+0], acc[4*q+1]);
            w.y = pack2(acc[4*q+2], acc[4*q+3]);
            ((uint2*)Af)[ir * 64 + g * 32 + mt * 4 + q] = w;
        }
    }
}

// ---------------------------------------------------------------------------
// Fused, SUPERTILE-PAIRED: each wave owns a 64-row supertile = two 32-row
// tiles (A: rows 0-31, B: rows 32-63) pushed through the mt loop together:
//  - one W1b/W2 ds_read feeds BOTH tiles' MFMAs (weight-LDS reads per tile
//    halved) and A/B give two independent MFMA dependency chains (ILP x2).
//  - a 64-row supertile touches <=4 distinct Af rows (segment runs >=8,
//    64-aligned windows of pattern [8,16,32,72]); found via 64-bit ballot,
//    staged with 4 coalesced 512B loads into double-buffered per-wave sAf.
//  - next supertile's SEG/ballot/Af loads issued under the current mt loop.
// 512 blocks x 512 thr; 8192 supertiles / 4096 waves = exactly 2 each.
// LDS: 32 (W1b) + 64 (W2) + 32 (sAf dbuf) = 128 KB. No barriers in main loop.
// ---------------------------------------------------------------------------
__global__ __launch_bounds__(512, 2) void fused_mlp(
    const float* __restrict__ ME,      // [524288, 64]
    const int*   __restrict__ SEG,     // [16384]
    const f16*   __restrict__ Af,      // [16384, 256] permuted
    const f16x8* __restrict__ pW1b,    // [8][4][64] frags
    const f16x8* __restrict__ pW2,     // [4][16][64] frags
    const float* __restrict__ B2,      // [128]
    const float* __restrict__ W3,      // [128]
    const float* __restrict__ B3,      // [1]
    float* __restrict__ OUT)           // [524288]
{
    __shared__ f16x8 sW1b[2048];          // 32 KB
    __shared__ f16x8 sW2[4096];           // 64 KB
    __shared__ uint2 sAf[8][2][256];      // 8 waves x dbuf x (4 slots x 512 B)

    const int tid = threadIdx.x, wid = tid >> 6, lane = tid & 63;
    const int g = lane >> 5, ln = lane & 31;

    #pragma unroll
    for (int i = 0; i < 4; ++i) sW1b[i * 512 + tid] = pW1b[i * 512 + tid];
    #pragma unroll
    for (int i = 0; i < 8; ++i) sW2[i * 512 + tid]  = pW2[i * 512 + tid];
    __syncthreads();

    // XCD-bijective block swizzle (512 % 8 == 0)
    const int bswz  = ((int)blockIdx.x & 7) * 64 + ((int)blockIdx.x >> 3);
    const int gwave = bswz * 8 + wid;      // 4096 waves; supertiles 0..8191

    const uint2* AB8 = (const uint2*)Af;   // 8B units: row*64 + u
    const float4* b24 = (const float4*)B2;
    const float4* w34 = (const float4*)W3;
    const float  b3v  = B3[0];

    // ---- prologue for supertile 0: SEG, ballot, <=4 rows, coalesced loads
    int st = gwave;
    int sv = SEG[((st & 255) << 6) + lane];    // lane = supertile row
    uint2 av0, av1, av2, av3;
    int slotA, slotB;
    {
        const int prev = __shfl_up(sv, 1);
        const u64 mk = __ballot((lane == 0) || (sv != prev));
        u64 m = mk;
        const int p0 = __builtin_ctzll(m); m &= m - 1;
        const int p1 = m ? __builtin_ctzll(m) : p0; m &= m - 1;
        const int p2 = m ? __builtin_ctzll(m) : p1; m &= m - 1;
        const int p3 = m ? __builtin_ctzll(m) : p2;
        const int base = (st >> 8) << 9;
        const int r0 = base + __builtin_amdgcn_readlane(sv, p0);
        const int r1 = base + __builtin_amdgcn_readlane(sv, p1);
        const int r2 = base + __builtin_amdgcn_readlane(sv, p2);
        const int r3 = base + __builtin_amdgcn_readlane(sv, p3);
        av0 = AB8[(long)r0 * 64 + lane];
        av1 = AB8[(long)r1 * 64 + lane];
        av2 = AB8[(long)r2 * 64 + lane];
        av3 = AB8[(long)r3 * 64 + lane];
        slotA = __builtin_popcountll(mk & ((2ull << ln) - 1)) - 1;
        slotB = __builtin_popcountll(mk & ((2ull << (ln + 32)) - 1)) - 1;
    }

    #pragma unroll
    for (int it = 0; it < 2; ++it) {
        const long row_base = (long)st << 6;
        // commit staged Af rows to this supertile's LDS buffer
        sAf[wid][it][0 * 64 + lane] = av0;
        sAf[wid][it][1 * 64 + lane] = av1;
        sAf[wid][it][2 * 64 + lane] = av2;
        sAf[wid][it][3 * 64 + lane] = av3;

        // issue next supertile's SEG read (covered by ME loads + mt loop)
        const int stn = st + 4096;
        int sv_n = 0;
        if (it == 0) sv_n = SEG[((stn & 255) << 6) + lane];

        // ME fragments for tiles A and B (k = 16s + 8g + j)
        f16x8 mefA[4], mefB[4];
        {
            const float4* mbA = (const float4*)(ME + (row_base + ln) * 64);
            const float4* mbB = (const float4*)(ME + (row_base + 32 + ln) * 64);
            #pragma unroll
            for (int s = 0; s < 4; ++s)
                mefA[s] = cvt8(mbA[4*s + 2*g], mbA[4*s + 2*g + 1]);
            #pragma unroll
            for (int s = 0; s < 4; ++s)
                mefB[s] = cvt8(mbB[4*s + 2*g], mbB[4*s + 2*g + 1]);
        }

        // next supertile's ballot + Af loads (hidden under the mt loop)
        int slotA_n = 0, slotB_n = 0;
        if (it == 0) {
            const int prev = __shfl_up(sv_n, 1);
            const u64 mk = __ballot((lane == 0) || (sv_n != prev));
            u64 m = mk;
            const int p0 = __builtin_ctzll(m); m &= m - 1;
            const int p1 = m ? __builtin_ctzll(m) : p0; m &= m - 1;
            const int p2 = m ? __builtin_ctzll(m) : p1; m &= m - 1;
            const int p3 = m ? __builtin_ctzll(m) : p2;
            const int base = (stn >> 8) << 9;
            const int r0 = base + __builtin_amdgcn_readlane(sv_n, p0);
            const int r1 = base + __builtin_amdgcn_readlane(sv_n, p1);
            const int r2 = base + __builtin_amdgcn_readlane(sv_n, p2);
            const int r3 = base + __builtin_amdgcn_readlane(sv_n, p3);
            av0 = AB8[(long)r0 * 64 + lane];
            av1 = AB8[(long)r1 * 64 + lane];
            av2 = AB8[(long)r2 * 64 + lane];
            av3 = AB8[(long)r3 * 64 + lane];
            slotA_n = __builtin_popcountll(mk & ((2ull << ln) - 1)) - 1;
            slotB_n = __builtin_popcountll(mk & ((2ull << (ln + 32)) - 1)) - 1;
        }

        f32x16 acc2A[4], acc2B[4];
        #pragma unroll
        for (int m2 = 0; m2 < 4; ++m2)
            #pragma unroll
            for (int i = 0; i < 16; ++i) { acc2A[m2][i] = 0.f; acc2B[m2][i] = 0.f; }

        const uint4* afp = (const uint4*)&sAf[wid][it][0];   // 16B units
        const int baseA = slotA * 32 + g * 16;
        const int baseB = slotB * 32 + g * 16;

        #pragma unroll
        for (int mt = 0; mt < 8; ++mt) {
            // Af chunks (broadcast LDS reads, <=4 distinct addrs per half-wave)
            const uint4 a0A = afp[baseA + 2*mt], a1A = afp[baseA + 2*mt + 1];
            const uint4 a0B = afp[baseB + 2*mt], a1B = afp[baseB + 2*mt + 1];

            // W1b fragments read ONCE, feed both tiles
            f16x8 w1bf[4];
            #pragma unroll
            for (int s = 0; s < 4; ++s) w1bf[s] = sW1b[(mt * 4 + s) * 64 + lane];

            f32x16 accA, accB;
            #pragma unroll
            for (int i = 0; i < 16; ++i) { accA[i] = 0.f; accB[i] = 0.f; }
            #pragma unroll
            for (int s = 0; s < 4; ++s) {       // two independent MFMA chains
                accA = MFMA32(w1bf[s], mefA[s], accA, 0, 0, 0);
                accB = MFMA32(w1bf[s], mefB[s], accB, 0, 0, 0);
            }

            // h1 = relu(A + mw) packed f16, both tiles
            u32 hptA[8], hptB[8];
            hptA[0] = pk_relu(pk_add(pack2(accA[0],  accA[1]),  a0A.x));
            hptA[1] = pk_relu(pk_add(pack2(accA[2],  accA[3]),  a0A.y));
            hptA[2] = pk_relu(pk_add(pack2(accA[4],  accA[5]),  a0A.z));
            hptA[3] = pk_relu(pk_add(pack2(accA[6],  accA[7]),  a0A.w));
            hptA[4] = pk_relu(pk_add(pack2(accA[8],  accA[9]),  a1A.x));
            hptA[5] = pk_relu(pk_add(pack2(accA[10], accA[11]), a1A.y));
            hptA[6] = pk_relu(pk_add(pack2(accA[12], accA[13]), a1A.z));
            hptA[7] = pk_relu(pk_add(pack2(accA[14], accA[15]), a1A.w));
            hptB[0] = pk_relu(pk_add(pack2(accB[0],  accB[1]),  a0B.x));
            hptB[1] = pk_relu(pk_add(pack2(accB[2],  accB[3]),  a0B.y));
            hptB[2] = pk_relu(pk_add(pack2(accB[4],  accB[5]),  a0B.z));
            hptB[3] = pk_relu(pk_add(pack2(accB[6],  accB[7]),  a0B.w));
            hptB[4] = pk_relu(pk_add(pack2(accB[8],  accB[9]),  a1B.x));
            hptB[5] = pk_relu(pk_add(pack2(accB[10], accB[11]), a1B.y));
            hptB[6] = pk_relu(pk_add(pack2(accB[12], accB[13]), a1B.z));
            hptB[7] = pk_relu(pk_add(pack2(accB[14], accB[15]), a1B.w));

            // layer-2 feed: ks2 = 2*mt + tt; W2 read ONCE, feeds both tiles
            #pragma unroll
            for (int tt = 0; tt < 2; ++tt) {
                u32 wA0 = hptA[4*tt+0], wA1 = hptA[4*tt+1];
                u32 wA2 = hptA[4*tt+2], wA3 = hptA[4*tt+3];
                asm("v_permlane32_swap_b32 %0, %1" : "+v"(wA0), "+v"(wA2));
                asm("v_permlane32_swap_b32 %0, %1" : "+v"(wA1), "+v"(wA3));
                u32 wB0 = hptB[4*tt+0], wB1 = hptB[4*tt+1];
                u32 wB2 = hptB[4*tt+2], wB3 = hptB[4*tt+3];
                asm("v_permlane32_swap_b32 %0, %1" : "+v"(wB0), "+v"(wB2));
                asm("v_permlane32_swap_b32 %0, %1" : "+v"(wB1), "+v"(wB3));
                int wvA[4] = {(int)wA0, (int)wA1, (int)wA2, (int)wA3};
                int wvB[4] = {(int)wB0, (int)wB1, (int)wB2, (int)wB3};
                f16x8 bfA, bfB;
                __builtin_memcpy(&bfA, wvA, 16);
                __builtin_memcpy(&bfB, wvB, 16);
                const int ks2 = 2 * mt + tt;
                f16x8 w2f[4];
                #pragma unroll
                for (int m2 = 0; m2 < 4; ++m2)
                    w2f[m2] = sW2[(m2 * 16 + ks2) * 64 + lane];
                #pragma unroll
                for (int m2 = 0; m2 < 4; ++m2) {   // 8 interleaved chains
                    acc2A[m2] = MFMA32(w2f[m2], bfA, acc2A[m2], 0, 0, 0);
                    acc2B[m2] = MFMA32(w2f[m2], bfB, acc2B[m2], 0, 0, 0);
                }
            }
        }

        // phase 3: out = relu(h2 + b2) . W3 + b3, both tiles
        float sumA = 0.f, sumB = 0.f;
        #pragma unroll
        for (int m2 = 0; m2 < 4; ++m2)
            #pragma unroll
            for (int q = 0; q < 4; ++q) {
                float4 bb = b24[8*m2 + 2*q + g];
                float4 ww = w34[8*m2 + 2*q + g];
                sumA += fmaxf(acc2A[m2][4*q+0] + bb.x, 0.f) * ww.x
                      + fmaxf(acc2A[m2][4*q+1] + bb.y, 0.f) * ww.y
                      + fmaxf(acc2A[m2][4*q+2] + bb.z, 0.f) * ww.z
                      + fmaxf(acc2A[m2][4*q+3] + bb.w, 0.f) * ww.w;
                sumB += fmaxf(acc2B[m2][4*q+0] + bb.x, 0.f) * ww.x
                      + fmaxf(acc2B[m2][4*q+1] + bb.y, 0.f) * ww.y
                      + fmaxf(acc2B[m2][4*q+2] + bb.z, 0.f) * ww.z
                      + fmaxf(acc2B[m2][4*q+3] + bb.w, 0.f) * ww.w;
            }
        sumA += __shfl_xor(sumA, 32, 64);
        sumB += __shfl_xor(sumB, 32, 64);
        if (lane < 32) {
            OUT[row_base + ln]      = sumA + b3v;
            OUT[row_base + 32 + ln] = sumB + b3v;
        }

        st = stn; sv = sv_n; slotA = slotA_n; slotB = slotB_n;
    }
}

// ---------------------------------------------------------------------------
extern "C" void kernel_launch(void* const* d_in, const int* in_sizes, int n_in,
                              void* d_out, int out_size, void* d_ws, size_t ws_size,
                              hipStream_t stream) {
    const float* h_inst = (const float*)d_in[0];
    const float* me     = (const float*)d_in[1];
    const int*   seg    = (const int*)d_in[2];
    const float* W1     = (const float*)d_in[3];
    const float* b1     = (const float*)d_in[4];
    const float* W2     = (const float*)d_in[5];
    const float* b2     = (const float*)d_in[6];
    const float* W3     = (const float*)d_in[7];
    const float* b3     = (const float*)d_in[8];
    float* out = (float*)d_out;

    char* ws = (char*)d_ws;
    f16* Af   = (f16*)ws;                                   // 8,388,608 B
    f16* pW1a = (f16*)(ws + 8388608);                       //   131,072 B
    f16* pW1b = (f16*)(ws + 8388608 + 131072);              //    32,768 B
    f16* pW2  = (f16*)(ws + 8388608 + 131072 + 32768);      //    65,536 B

    prepack<<<448, 256, 0, stream>>>(W1, W2, pW1a, pW1b, pW2);
    ainit<<<512, 256, 0, stream>>>(h_inst, (const f16x8*)pW1a, b1, Af);
    fused_mlp<<<512, 512, 0, stream>>>(me, seg, Af, (const f16x8*)pW1b,
                                       (const f16x8*)pW2, b2, W3, b3, out);
}

// Round 14
// 83.507 us; speedup vs baseline: 3.0980x; 1.0123x over previous
//
#include <hip/hip_runtime.h>

// B=32, N=512, D=256, M=64, HID=256, H2=128, T=16384, rows R=B*T=524288
typedef _Float16 f16;
typedef f16  f16x2 __attribute__((ext_vector_type(2)));
typedef f16  f16x8 __attribute__((ext_vector_type(8)));
typedef float f32x16 __attribute__((ext_vector_type(16)));
typedef unsigned int u32;

#define MFMA32 __builtin_amdgcn_mfma_f32_32x32x16_f16
#define NT 4   // row-tiles (32 rows) per wave

static __device__ __forceinline__ f16x8 cvt8(float4 a, float4 b) {
    f16x8 v;
    v[0]=(f16)a.x; v[1]=(f16)a.y; v[2]=(f16)a.z; v[3]=(f16)a.w;
    v[4]=(f16)b.x; v[5]=(f16)b.y; v[6]=(f16)b.z; v[7]=(f16)b.w;
    return v;
}
static __device__ __forceinline__ u32 pack2(float a, float b) {
    f16x2 p; p[0]=(f16)a; p[1]=(f16)b;
    return __builtin_bit_cast(u32, p);
}
static __device__ __forceinline__ u32 pk_add(u32 a, u32 b) {
    u32 d; asm("v_pk_add_f16 %0, %1, %2" : "=v"(d) : "v"(a), "v"(b)); return d;
}
static __device__ __forceinline__ u32 pk_relu(u32 a) {
    u32 d; asm("v_pk_max_f16 %0, %1, 0" : "=v"(d) : "v"(a)); return d;
}

// ---------------------------------------------------------------------------
// Prepack: W1a (256x256), W1b (64x256), W2 (256x128) -> f16 MFMA A-operand
// fragment layout for 32x32x16: frag[mt][ks][lane][j] = W[k][col],
// k = 16*ks + 8*(lane>>5) + j, col = 32*mt + (lane&31).
// ---------------------------------------------------------------------------
__global__ __launch_bounds__(256) void prepack(
    const float* __restrict__ W1, const float* __restrict__ W2,
    f16* __restrict__ pa, f16* __restrict__ pb, f16* __restrict__ pc)
{
    const int idx = blockIdx.x * 256 + threadIdx.x;   // grid covers 114688
    int rel, fid, mt, ks;
    const int lane = (idx >> 3) & 63;
    const int j    = idx & 7;
    const int g8   = ((lane >> 5) << 3) + j;
    const int ln   = lane & 31;
    if (idx < 65536) {                 // W1a: [8 mt][16 ks]
        rel = idx; fid = rel >> 9; mt = fid >> 4; ks = fid & 15;
        int k = 16 * ks + g8, col = 32 * mt + ln;
        pa[rel] = (f16)W1[k * 256 + col];
    } else if (idx < 81920) {          // W1b: [8 mt][4 ks]
        rel = idx - 65536; fid = rel >> 9; mt = fid >> 2; ks = fid & 3;
        int k = 16 * ks + g8, col = 32 * mt + ln;
        pb[rel] = (f16)W1[(256 + k) * 256 + col];
    } else {                           // W2: [4 mt][16 ks]
        rel = idx - 81920; fid = rel >> 9; mt = fid >> 4; ks = fid & 15;
        int k = 16 * ks + g8, col = 32 * mt + ln;
        pc[rel] = (f16)W2[k * 128 + col];
    }
}

// ---------------------------------------------------------------------------
// Kernel 1: A[ir][c] = sum_k h[ir][k] * W1a[k][c] + b1[c], stored f16 in a
// gather-friendly permuted layout: uint2 index = ir*64 + g*32 + mt*4 + q.
// ---------------------------------------------------------------------------
__global__ __launch_bounds__(256) void ainit(
    const float* __restrict__ H,       // [16384, 256]
    const f16x8* __restrict__ pW1a,    // [8][16][64] frags
    const float* __restrict__ B1,      // [256]
    f16* __restrict__ Af)              // [16384, 256] permuted
{
    const int tid = threadIdx.x, wid = tid >> 6, lane = tid & 63;
    const int g = lane >> 5, ln = lane & 31;
    const long ir = (long)blockIdx.x * 32 + ln;

    const float4* h4 = (const float4*)(H + ir * 256);
    f16x8 hf[16];
    #pragma unroll
    for (int ks = 0; ks < 16; ++ks)
        hf[ks] = cvt8(h4[4 * ks + 2 * g], h4[4 * ks + 2 * g + 1]);

    const float4* b14 = (const float4*)B1;
    #pragma unroll
    for (int mi = 0; mi < 2; ++mi) {
        const int mt = wid * 2 + mi;
        f32x16 acc;
        #pragma unroll
        for (int q = 0; q < 4; ++q) {
            float4 bv = b14[8 * mt + 2 * q + g];
            acc[4*q+0] = bv.x; acc[4*q+1] = bv.y; acc[4*q+2] = bv.z; acc[4*q+3] = bv.w;
        }
        #pragma unroll
        for (int ks = 0; ks < 16; ++ks)
            acc = MFMA32(pW1a[(mt * 16 + ks) * 64 + lane], hf[ks], acc, 0, 0, 0);
        #pragma unroll
        for (int q = 0; q < 4; ++q) {
            uint2 w;
            w.x = pack2(acc[4*q+0], acc[4*q+1]);
            w.y = pack2(acc[4*q+2], acc[4*q+3]);
            ((uint2*)Af)[ir * 64 + g * 32 + mt * 4 + q] = w;
        }
    }
}

// ---------------------------------------------------------------------------
// Fused kernel (R9 chassis + 4-chain L1 regroup):
//  - L1 computed s-outer over GROUPS of 4 mt => 4 independent MFMA dependency
//    chains (was 1/mt) — fills the ~64-cyc dependent-MFMA latency.
//  - pack/permlane/L2-feed per mt inside the group (VALU also 4x parallel).
//  - ME: coalesced float4 loads, f16-packed, LDS-bounced (R9).
//  - Af: <=3 distinct rows per tile via ballot; ONE coalesced load each,
//    staged to per-wave LDS slots (R9, fixed slot formula).
//  - W1b (32KB) + W2 (64KB) in LDS; no barriers in the main loop.
// ---------------------------------------------------------------------------
__global__ __launch_bounds__(512, 2) void fused_mlp(
    const float* __restrict__ ME,      // [524288, 64]
    const int*   __restrict__ SEG,     // [16384]
    const f16*   __restrict__ Af,      // [16384, 256] permuted
    const f16x8* __restrict__ pW1b,    // [8][4][64] frags
    const f16x8* __restrict__ pW2,     // [4][16][64] frags
    const float* __restrict__ B2,      // [128]
    const float* __restrict__ W3,      // [128]
    const float* __restrict__ B3,      // [1]
    float* __restrict__ OUT)           // [524288]
{
    __shared__ f16x8 sW1b[2048];       // 32 KB
    __shared__ f16x8 sW2[4096];        // 64 KB
    __shared__ uint2 sME[8][512];      // 8 waves x 4 KB (f16 tile, frag order)
    __shared__ uint2 sAf[8][256];      // 8 waves x 2 KB (slots x 512 B)

    const int tid = threadIdx.x, wid = tid >> 6, lane = tid & 63;
    const int g = lane >> 5, ln = lane & 31;

    #pragma unroll
    for (int i = 0; i < 4; ++i) sW1b[i * 512 + tid] = pW1b[i * 512 + tid];
    #pragma unroll
    for (int i = 0; i < 8; ++i) sW2[i * 512 + tid]  = pW2[i * 512 + tid];
    __syncthreads();

    // XCD-bijective block swizzle (512 % 8 == 0)
    const int bswz = (blockIdx.x & 7) * 64 + (blockIdx.x >> 3);
    const long gwave    = (long)bswz * 8 + wid;       // 4096 waves
    const long row_base = gwave * (NT * 32);          // 128 rows, same batch b
    const int  b     = (int)(row_base >> 14);
    const int  tloc0 = (int)(row_base & 16383);

    // ---- gather metadata per tile: <=3 distinct Af rows (segment runs >=8)
    int r0a[NT], r1a[NT], r2a[NT];     // uniform distinct row ids
    int slot[NT];                      // per-lane slot index (0..2)
    #pragma unroll
    for (int t = 0; t < NT; ++t) {
        const int ar   = SEG[tloc0 + t * 32 + ln];
        const int prev = __shfl_up(ar, 1);
        const u32 mk = (u32)__ballot((ln == 0) || (ar != prev));  // low 32 lanes
        u32 m = mk;
        const int p0 = __builtin_ctz(m); m &= m - 1;
        const int p1 = m ? __builtin_ctz(m) : p0; m &= m - 1;
        const int p2 = m ? __builtin_ctz(m) : p1;
        const int base = b << 9;
        r0a[t] = base + __builtin_amdgcn_readlane(ar, p0);
        r1a[t] = base + __builtin_amdgcn_readlane(ar, p1);
        r2a[t] = base + __builtin_amdgcn_readlane(ar, p2);
        // rank of this lane's run = (# boundaries at positions <= ln) - 1
        slot[t] = __popc(mk & ((2u << ln) - 1)) - 1;
    }

    const uint2* AB8 = (const uint2*)Af;   // 8B units: row*64 + u

    // ME write offset (uint2 units): lane holds fp32 chunk c=(l&15) of row
    // r=4i+(l>>4); f16 dest unit ((c>>1)*32 + r)*2 + (c&1).
    const int meW = (((lane & 15) >> 1) * 32 + (lane >> 4)) * 2 + (lane & 1);

    float4 mv[8]; uint2 av[3];
    #define ISSUE(t_) {                                                      \
        const float4* mb = (const float4*)(ME + (row_base + (t_) * 32) * 64);\
        _Pragma("unroll")                                                    \
        for (int i = 0; i < 8; ++i) mv[i] = mb[i * 64 + lane];               \
        av[0] = AB8[(long)r0a[t_] * 64 + lane];                              \
        av[1] = AB8[(long)r1a[t_] * 64 + lane];                              \
        av[2] = AB8[(long)r2a[t_] * 64 + lane];                              \
    }
    #define COMMIT() {                                                       \
        _Pragma("unroll")                                                    \
        for (int i = 0; i < 8; ++i) {                                        \
            uint2 w;                                                         \
            w.x = pack2(mv[i].x, mv[i].y);                                   \
            w.y = pack2(mv[i].z, mv[i].w);                                   \
            sME[wid][meW + i * 8] = w;                                       \
        }                                                                    \
        sAf[wid][0 * 64 + lane] = av[0];                                     \
        sAf[wid][1 * 64 + lane] = av[1];                                     \
        sAf[wid][2 * 64 + lane] = av[2];                                     \
    }

    ISSUE(0);
    COMMIT();

    const float4* b24 = (const float4*)B2;
    const float4* w34 = (const float4*)W3;
    const float  b3v  = B3[0];

    #pragma unroll
    for (int t = 0; t < NT; ++t) {
        if (t + 1 < NT) ISSUE(t + 1);          // covered by this tile's compute

        // ME fragments from LDS (conflict-free lane-linear b128)
        f16x8 mef[4];
        #pragma unroll
        for (int s = 0; s < 4; ++s)
            mef[s] = *(const f16x8*)&sME[wid][((2 * s + g) * 32 + ln) * 2];

        const uint4* afp = (const uint4*)&sAf[wid][0];   // 16B units
        const int afbase = slot[t] * 32 + g * 16;

        f32x16 acc2[4];
        #pragma unroll
        for (int m2 = 0; m2 < 4; ++m2)
            #pragma unroll
            for (int i = 0; i < 16; ++i) acc2[m2][i] = 0.f;

        // ---- two groups of 4 mt; s-outer => 4 independent L1 MFMA chains
        #pragma unroll
        for (int grp = 0; grp < 2; ++grp) {
            const int mt0 = grp * 4;

            f32x16 accL[4];
            #pragma unroll
            for (int i = 0; i < 4; ++i)
                #pragma unroll
                for (int k = 0; k < 16; ++k) accL[i][k] = 0.f;

            #pragma unroll
            for (int s = 0; s < 4; ++s) {
                f16x8 wf[4];
                #pragma unroll
                for (int i = 0; i < 4; ++i)
                    wf[i] = sW1b[((mt0 + i) * 4 + s) * 64 + lane];
                #pragma unroll
                for (int i = 0; i < 4; ++i)       // 4 independent chains
                    accL[i] = MFMA32(wf[i], mef[s], accL[i], 0, 0, 0);
            }

            // pack + permlane + L2 feed per mt of the group
            #pragma unroll
            for (int i = 0; i < 4; ++i) {
                const int mt = mt0 + i;
                const uint4 a0 = afp[afbase + 2 * mt];
                const uint4 a1 = afp[afbase + 2 * mt + 1];

                u32 hpt[8];
                hpt[0] = pk_relu(pk_add(pack2(accL[i][0],  accL[i][1]),  a0.x));
                hpt[1] = pk_relu(pk_add(pack2(accL[i][2],  accL[i][3]),  a0.y));
                hpt[2] = pk_relu(pk_add(pack2(accL[i][4],  accL[i][5]),  a0.z));
                hpt[3] = pk_relu(pk_add(pack2(accL[i][6],  accL[i][7]),  a0.w));
                hpt[4] = pk_relu(pk_add(pack2(accL[i][8],  accL[i][9]),  a1.x));
                hpt[5] = pk_relu(pk_add(pack2(accL[i][10], accL[i][11]), a1.y));
                hpt[6] = pk_relu(pk_add(pack2(accL[i][12], accL[i][13]), a1.z));
                hpt[7] = pk_relu(pk_add(pack2(accL[i][14], accL[i][15]), a1.w));

                #pragma unroll
                for (int tt = 0; tt < 2; ++tt) {
                    u32 w0 = hpt[4*tt+0], w1 = hpt[4*tt+1];
                    u32 w2 = hpt[4*tt+2], w3 = hpt[4*tt+3];
                    asm("v_permlane32_swap_b32 %0, %1" : "+v"(w0), "+v"(w2));
                    asm("v_permlane32_swap_b32 %0, %1" : "+v"(w1), "+v"(w3));
                    int wv[4] = {(int)w0, (int)w1, (int)w2, (int)w3};
                    f16x8 bf;
                    __builtin_memcpy(&bf, wv, 16);
                    const int ks2 = 2 * mt + tt;
                    __builtin_amdgcn_s_setprio(1);
                    #pragma unroll
                    for (int m2 = 0; m2 < 4; ++m2)
                        acc2[m2] = MFMA32(sW2[(m2 * 16 + ks2) * 64 + lane], bf, acc2[m2], 0, 0, 0);
                    __builtin_amdgcn_s_setprio(0);
                }
            }
        }

        // phase 3: out = relu(h2 + b2) . W3 + b3
        float sum = 0.f;
        #pragma unroll
        for (int m2 = 0; m2 < 4; ++m2)
            #pragma unroll
            for (int q = 0; q < 4; ++q) {
                float4 bb = b24[8*m2 + 2*q + g];
                float4 ww = w34[8*m2 + 2*q + g];
                sum += fmaxf(acc2[m2][4*q+0] + bb.x, 0.f) * ww.x
                     + fmaxf(acc2[m2][4*q+1] + bb.y, 0.f) * ww.y
                     + fmaxf(acc2[m2][4*q+2] + bb.z, 0.f) * ww.z
                     + fmaxf(acc2[m2][4*q+3] + bb.w, 0.f) * ww.w;
            }
        sum += __shfl_xor(sum, 32, 64);
        if (lane < 32) OUT[row_base + t * 32 + ln] = sum + b3v;

        if (t + 1 < NT) COMMIT();              // stage next tile's LDS data
    }
    #undef ISSUE
    #undef COMMIT
}

// ---------------------------------------------------------------------------
extern "C" void kernel_launch(void* const* d_in, const int* in_sizes, int n_in,
                              void* d_out, int out_size, void* d_ws, size_t ws_size,
                              hipStream_t stream) {
    const float* h_inst = (const float*)d_in[0];
    const float* me     = (const float*)d_in[1];
    const int*   seg    = (const int*)d_in[2];
    const float* W1     = (const float*)d_in[3];
    const float* b1     = (const float*)d_in[4];
    const float* W2     = (const float*)d_in[5];
    const float* b2     = (const float*)d_in[6];
    const float* W3     = (const float*)d_in[7];
    const float* b3     = (const float*)d_in[8];
    float* out = (float*)d_out;

    char* ws = (char*)d_ws;
    f16* Af   = (f16*)ws;                                   // 8,388,608 B
    f16* pW1a = (f16*)(ws + 8388608);                       //   131,072 B
    f16* pW1b = (f16*)(ws + 8388608 + 131072);              //    32,768 B
    f16* pW2  = (f16*)(ws + 8388608 + 131072 + 32768);      //    65,536 B

    prepack<<<448, 256, 0, stream>>>(W1, W2, pW1a, pW1b, pW2);
    ainit<<<512, 256, 0, stream>>>(h_inst, (const f16x8*)pW1a, b1, Af);
    fused_mlp<<<512, 512, 0, stream>>>(me, seg, Af, (const f16x8*)pW1b,
                                       (const f16x8*)pW2, b2, W3, b3, out);
}